// Round 11
// baseline (155.894 us; speedup 1.0000x reference)
//
#include <hip/hip_runtime.h>
#include <hip/hip_bf16.h>

#define DM 512
#define NTOK 1024
#define NB 16

typedef _Float16 f16;
typedef _Float16 half8 __attribute__((ext_vector_type(8)));
typedef _Float16 half4_t __attribute__((ext_vector_type(4)));
typedef float f32x4 __attribute__((ext_vector_type(4)));

__device__ __forceinline__ void gload16(const void* g, void* l) {
    __builtin_amdgcn_global_load_lds(
        (const __attribute__((address_space(1))) void*)g,
        (__attribute__((address_space(3))) void*)l, 16, 0, 0);
}

// ---------------- prep: transpose_x (blocks 0..8191) + convert_wqkv (8192..11263) ----------------
__global__ __launch_bounds__(256)
void prep_kernel(const float* __restrict__ x, f16* __restrict__ xt,
                 const float* __restrict__ Wq, const float* __restrict__ Wk,
                 const float* __restrict__ Wv, const float* __restrict__ bq,
                 const float* __restrict__ bk, const float* __restrict__ bv,
                 f16* __restrict__ wdst, float* __restrict__ bdst,
                 float* __restrict__ rowsum) {
    __shared__ float tile[32][33];
    int bid = blockIdx.x, tid = threadIdx.x;
    if (bid < 8192) {
        // transpose_x: x f32 [B][C][N] -> xt f16 [B][N][C]
        int b = bid >> 9, byy = (bid >> 5) & 15, bxx = bid & 31;
        int n0 = bxx * 32, c0 = byy * 32;
        int tx = tid & 7, ty = tid >> 3;   // 8 x 32
        const float* xb = x + (size_t)b * DM * NTOK + (size_t)(c0 + ty) * NTOK + n0 + tx * 4;
        float4 v = *(const float4*)xb;
        tile[ty][tx * 4 + 0] = v.x; tile[ty][tx * 4 + 1] = v.y;
        tile[ty][tx * 4 + 2] = v.z; tile[ty][tx * 4 + 3] = v.w;
        __syncthreads();
        half4_t h = {(f16)tile[tx * 4 + 0][ty], (f16)tile[tx * 4 + 1][ty],
                     (f16)tile[tx * 4 + 2][ty], (f16)tile[tx * 4 + 3][ty]};
        *(half4_t*)&xt[(size_t)b * NTOK * DM + (size_t)(n0 + ty) * DM + c0 + tx * 4] = h;
    } else {
        int c = bid - 8192;                // 0..3071
        int i = c * 256 + tid;             // 0..786431
        int row = i >> 9, col = i & 511;
        float v = (row < 512) ? Wq[i] : (row < 1024) ? Wk[(row - 512) * 512 + col]
                                                     : Wv[(row - 1024) * 512 + col];
        wdst[i] = (f16)v;
        if (i < 1536)
            bdst[i] = (i < 512) ? bq[i] : (i < 1024) ? bk[i - 512] : bv[i - 1024];
        if (c < 64) rowsum[c * 256 + tid] = 0.f;  // 16384 f32
    }
}

// ---------------- NT GEMM: D[i][j] = sum_k A[i][k]*B[j][k], 128x128 tile, 4 waves ----------------
// BK=64 + both-sides XOR swizzle (r8) + T1 XCD-aware bijective block remap (r9).
// Launch is 1D flat with NWG = GX*GY*NB GEMM blocks + XB extra streaming-role blocks
// whose memory traffic fills the GEMM's drain-stall bubbles (r10 proven pattern):
//   MODE 2 extras: mid role — Wo f32->f16 convert (1024 blks) + vtok->vh transpose (8192 blks).
//     deps: reads vtok (prev dispatch), writes woh/vh (next dispatches) — race-free.
//   MODE 3 extras: finalize role — e16 -> normalized f32 attn, 8 exclusive rows/block.
// MODE 0: QKV — gj<1024: f16 qk=D+bias[gj]; gj>=1024: f16 vtok[z][gi][gj-1024]=D+bias[gj]
// MODE 2: scores — e=exp(min(D*scale,14)-4) -> f16 e-slot (upper 2KB of attn row) + rowsum atomics
// MODE 3: out-proj — f32 out0 = D + bias[gi] + resid
// MODE 5: PV — f16 out = D * (1/rowsum[gi])
template<int MODE, int KC, int GX, int GY, int XB>
__global__ __launch_bounds__(256)
void gemm_nt(const f16* __restrict__ A, const f16* __restrict__ B, void* __restrict__ Cout,
             const float* __restrict__ bias, const float* __restrict__ resid,
             f16* __restrict__ aux, float* __restrict__ rowsum, float* __restrict__ fin,
             const float* __restrict__ Wo, f16* __restrict__ woh,
             const f16* __restrict__ vtok, f16* __restrict__ vh,
             int ldA, int ldB, int ldC,
             long sA, long sB, long sC, long sR, float scale) {
    __shared__ f16 As[128 * 64];
    __shared__ f16 Bs[128 * 64];

    constexpr int NWG = GX * GY * NB;
    int flat = blockIdx.x;
    int tid = threadIdx.x;

    if (MODE == 3 && XB > 0 && flat >= NWG) {
        // ---- finalize role: 8 exclusive attn rows; read-all -> sync -> write-all ----
        int row0 = (flat - NWG) * 8;
        const f16* eb = (const f16*)fin;
        half4_t h[8];
#pragma unroll
        for (int rr = 0; rr < 8; ++rr)
            h[rr] = *(const half4_t*)(eb + (size_t)(row0 + rr) * 2048 + 1024 + tid * 4);
        __syncthreads();
#pragma unroll
        for (int rr = 0; rr < 8; ++rr) {
            int row = row0 + rr;
            float inv = 1.0f / rowsum[row];
            float4 o = {(float)h[rr][0] * inv, (float)h[rr][1] * inv,
                        (float)h[rr][2] * inv, (float)h[rr][3] * inv};
            *(float4*)(fin + (size_t)row * 1024 + tid * 4) = o;
        }
        return;
    }

    if (MODE == 2 && XB > 0 && flat >= NWG) {
        // ---- mid role: Wo convert (c<1024) or vtok->vh transpose (c>=1024) ----
        int c = flat - NWG;
        if (c < 1024) {
            int i = c * 256 + tid;
            woh[i] = (f16)Wo[i];
        } else {
            c -= 1024;                     // 0..8191
            f16 (*tile)[36] = (f16(*)[36])As;   // reuse GEMM LDS
            int b = c >> 9, byy = (c >> 5) & 15, bxx = c & 31;
            int n0 = bxx * 32, c0 = byy * 32;
            int tx = tid & 7, ty = tid >> 3;    // 8 x 32
            const f16* src = vtok + (size_t)b * NTOK * DM + (size_t)(n0 + ty) * DM + c0 + tx * 4;
            half4_t v = *(const half4_t*)src;
            tile[ty][tx * 4 + 0] = v[0]; tile[ty][tx * 4 + 1] = v[1];
            tile[ty][tx * 4 + 2] = v[2]; tile[ty][tx * 4 + 3] = v[3];
            __syncthreads();
            half4_t h = {tile[tx * 4 + 0][ty], tile[tx * 4 + 1][ty],
                         tile[tx * 4 + 2][ty], tile[tx * 4 + 3][ty]};
            *(half4_t*)&vh[(size_t)b * DM * NTOK + (size_t)(c0 + ty) * NTOK + n0 + tx * 4] = h;
        }
        return;
    }

    // T1: XCD-aware bijective remap (NWG % 8 == 0 for all instantiations)
    int w = (flat & 7) * (NWG >> 3) + (flat >> 3);
    int bx = w % GX, by = (w / GX) % GY, bz = w / (GX * GY);

    int z = bz;
    const f16* Ab = A + (size_t)z * sA;
    const f16* Bb = B + (size_t)z * sB;
    int wave = tid >> 6, lane = tid & 63;
    int wr = wave >> 1, wc = wave & 1;
    int tI = by * 128, tJ = bx * 128;

    f32x4 acc[4][4];
#pragma unroll
    for (int m = 0; m < 4; ++m)
#pragma unroll
        for (int n = 0; n < 4; ++n) acc[m][n] = (f32x4){0.f, 0.f, 0.f, 0.f};

    int frow = lane & 15, fks = lane >> 4;   // fragment row-low, 16B-slot base

    for (int k0 = 0; k0 < KC; k0 += 64) {
        // STAGE: 1024 16B-slots each for A,B; linear LDS dest, source col inverse-swizzled
#pragma unroll
        for (int h = 0; h < 4; ++h) {
            int L = h * 256 + tid;           // slot 0..1023
            int r = L >> 3;                  // row 0..127
            int gc = ((L & 7) ^ (r & 7)) * 8;
            gload16(Ab + (size_t)(tI + r) * ldA + k0 + gc, &As[L * 8]);
            gload16(Bb + (size_t)(tJ + r) * ldB + k0 + gc, &Bs[L * 8]);
        }
        asm volatile("s_waitcnt vmcnt(0)" ::: "memory");
        __syncthreads();

#pragma unroll
        for (int ks = 0; ks < 2; ++ks) {
            half8 af[4], bf[4];
            int s = ks * 4 + fks;            // natural 16B-slot 0..7
#pragma unroll
            for (int m = 0; m < 4; ++m) {
                int R = wr * 64 + m * 16 + frow;
                af[m] = *(const half8*)&As[R * 64 + ((s ^ (R & 7)) << 3)];
            }
#pragma unroll
            for (int n = 0; n < 4; ++n) {
                int R = wc * 64 + n * 16 + frow;
                bf[n] = *(const half8*)&Bs[R * 64 + ((s ^ (R & 7)) << 3)];
            }
#pragma unroll
            for (int m = 0; m < 4; ++m)
#pragma unroll
                for (int n = 0; n < 4; ++n)
                    acc[m][n] = __builtin_amdgcn_mfma_f32_16x16x32_f16(af[m], bf[n], acc[m][n], 0, 0, 0);
        }
        __syncthreads();
    }

    // epilogue: D row = (lane>>4)*4 + r, col = lane&15  (verified m89 mapping)
    int ro = (lane >> 4) * 4, co = lane & 15;
#pragma unroll
    for (int m = 0; m < 4; ++m) {
#pragma unroll
        for (int r = 0; r < 4; ++r) {
            int gi = tI + wr * 64 + m * 16 + ro + r;
            float rs = 0.f, inv = 0.f;
            if (MODE == 5) inv = 1.0f / rowsum[z * 1024 + gi];
#pragma unroll
            for (int n = 0; n < 4; ++n) {
                int gj = tJ + wc * 64 + n * 16 + co;
                float v = acc[m][n][r];
                if (MODE == 0) {
                    v += bias[gj];
                    if (gj < 1024)   // block-uniform branch (tile never straddles 1024)
                        ((f16*)Cout)[(size_t)z * sC + (size_t)gi * ldC + gj] = (f16)v;
                    else             // V token-major, coalesced
                        aux[(size_t)z * 524288 + (size_t)gi * 512 + (gj - 1024)] = (f16)v;
                } else if (MODE == 2) {
                    float e = __expf(fminf(v * scale, 14.f) - 4.f);
                    // e-slot: f16 in the upper 2KB of attn row gi's 4KB slot
                    ((f16*)Cout)[((size_t)z * 1024 + gi) * 2048 + 1024 + gj] = (f16)e;
                    rs += e;
                } else if (MODE == 3) {
                    ((float*)Cout)[(size_t)z * sC + (size_t)gi * ldC + gj] =
                        v + bias[gi] + resid[(size_t)z * sR + (size_t)gi * ldC + gj];
                } else {  // MODE 5
                    ((f16*)Cout)[(size_t)z * sC + (size_t)gi * ldC + gj] = (f16)(v * inv);
                }
            }
            if (MODE == 2) {
                rs += __shfl_xor(rs, 1, 16);
                rs += __shfl_xor(rs, 2, 16);
                rs += __shfl_xor(rs, 4, 16);
                rs += __shfl_xor(rs, 8, 16);
                if ((lane & 15) == 0) atomicAdd(&rowsum[z * 1024 + gi], rs);
            }
        }
    }
}

extern "C" void kernel_launch(void* const* d_in, const int* in_sizes, int n_in,
                              void* d_out, int out_size, void* d_ws, size_t ws_size,
                              hipStream_t stream) {
    const float* x  = (const float*)d_in[0];
    const float* Wq = (const float*)d_in[1];
    const float* bq = (const float*)d_in[2];
    const float* Wk = (const float*)d_in[3];
    const float* bk = (const float*)d_in[4];
    const float* Wv = (const float*)d_in[5];
    const float* bv = (const float*)d_in[6];
    const float* Wo = (const float*)d_in[7];
    const float* bo = (const float*)d_in[8];

    float* out0 = (float*)d_out;                           // [16][512][1024]
    float* attn = (float*)d_out + (size_t)NB * DM * NTOK;  // [16][1024][1024] f32 (+e16 slots)

    // workspace layout (f16 units), peak 34,376,704 units = 68.75 MB (proven budget)
    f16* ws    = (f16*)d_ws;
    f16* xt    = ws;                        // [B][N][512]   8,388,608 (dead after QKV)
    f16* oh    = ws;                        // [B][N][512]   alias of xt
    f16* qk    = ws + 8388608;              // [B][N][1024] 16,777,216 (q cols 0..511, k cols 512..1023)
    f16* vh    = ws + 25165824;             // [B][512][N]   8,388,608
    f16* wqkvh = ws + 33554432;             // [1536][512]     786,432
    f16* woh   = ws + 33554432;             // [512][512]    alias of wqkvh
    float* bqkv   = (float*)(ws + 34340864);  // [1536] f32
    float* rowsum = (float*)(ws + 34343936);  // [16384] f32

    // vtok lives in the out0 region of d_out (dead until the final GEMM)
    f16* vtok = (f16*)out0;                 // [B][N][512] f16 = 16 MB of out0's 32 MB

    const long sTok   = (long)NTOK * DM;      // 524288
    const long sQK    = (long)NTOK * 1024;    // 1048576
    const long sEslot = (long)NTOK * 2048;    // 2097152 (f16 units per batch of e-slot rows)
    const float scal = 0.044194173824159216f;  // 1/sqrt(512)

    // 1) prep: x transpose+convert, W_qkv concat-convert, bias concat, rowsum zero
    prep_kernel<<<8192 + 3072, 256, 0, stream>>>(x, xt, Wq, Wk, Wv, bq, bk, bv,
                                                 wqkvh, bqkv, rowsum);

    // 2) fused QKV: q,k -> qk[b][tok][0..1023]; V -> vtok[b][tok][0..511]
    gemm_nt<0, 512, 12, 8, 0><<<12 * 8 * NB, 256, 0, stream>>>(xt, wqkvh, qk, bqkv, nullptr,
        vtok, nullptr, nullptr, nullptr, nullptr, nullptr, nullptr,
        512, 512, 1024, sTok, 0, sQK, 0, 0.f);

    // 3) scores (+ mid role blocks: Wo convert into woh, vtok -> vh channel-major)
    gemm_nt<2, 512, 8, 8, 9216><<<8 * 8 * NB + 9216, 256, 0, stream>>>(qk, qk + 512, attn,
        nullptr, nullptr, nullptr, rowsum, nullptr, Wo, woh, vtok, vh,
        1024, 1024, 0, sQK, sQK, 0, 0, scal);

    // 4) PV: O = (e·V^T)·inv_l -> oh [B][N][512] f16   (e-slots read here, destroyed next)
    gemm_nt<5, 1024, 4, 8, 0><<<4 * 8 * NB, 256, 0, stream>>>((const f16*)attn + 1024, vh, oh,
        nullptr, nullptr, nullptr, rowsum, nullptr, nullptr, nullptr, nullptr, nullptr,
        2048, 1024, 512, sEslot, sTok, sTok, 0, 0.f);

    // 5) out0 = Wo·O^T + bo + x, plus 2048 finalize-role blocks (e16 -> normalized f32 attn)
    gemm_nt<3, 512, 8, 4, 2048><<<8 * 4 * NB + 2048, 256, 0, stream>>>(woh, oh, out0, bo, x,
        nullptr, rowsum, attn, nullptr, nullptr, nullptr, nullptr,
        512, 512, 1024, 0, sTok, sTok, sTok, 0.f);
}

// Round 12
// 151.868 us; speedup vs baseline: 1.0265x; 1.0265x over previous
//
#include <hip/hip_runtime.h>
#include <hip/hip_bf16.h>

#define DM 512
#define NTOK 1024
#define NB 16

typedef _Float16 f16;
typedef _Float16 half8 __attribute__((ext_vector_type(8)));
typedef _Float16 half4_t __attribute__((ext_vector_type(4)));
typedef float f32x4 __attribute__((ext_vector_type(4)));

__device__ __forceinline__ void gload16(const void* g, void* l) {
    __builtin_amdgcn_global_load_lds(
        (const __attribute__((address_space(1))) void*)g,
        (__attribute__((address_space(3))) void*)l, 16, 0, 0);
}

// ---------------- prep: transpose_x (blocks 0..8191) + convert_wqkv (8192..11263) ----------------
__global__ __launch_bounds__(256)
void prep_kernel(const float* __restrict__ x, f16* __restrict__ xt,
                 const float* __restrict__ Wq, const float* __restrict__ Wk,
                 const float* __restrict__ Wv, const float* __restrict__ bq,
                 const float* __restrict__ bk, const float* __restrict__ bv,
                 f16* __restrict__ wdst, float* __restrict__ bdst,
                 float* __restrict__ rowsum) {
    __shared__ float tile[32][33];
    int bid = blockIdx.x, tid = threadIdx.x;
    if (bid < 8192) {
        // transpose_x: x f32 [B][C][N] -> xt f16 [B][N][C]
        int b = bid >> 9, byy = (bid >> 5) & 15, bxx = bid & 31;
        int n0 = bxx * 32, c0 = byy * 32;
        int tx = tid & 7, ty = tid >> 3;   // 8 x 32
        const float* xb = x + (size_t)b * DM * NTOK + (size_t)(c0 + ty) * NTOK + n0 + tx * 4;
        float4 v = *(const float4*)xb;
        tile[ty][tx * 4 + 0] = v.x; tile[ty][tx * 4 + 1] = v.y;
        tile[ty][tx * 4 + 2] = v.z; tile[ty][tx * 4 + 3] = v.w;
        __syncthreads();
        half4_t h = {(f16)tile[tx * 4 + 0][ty], (f16)tile[tx * 4 + 1][ty],
                     (f16)tile[tx * 4 + 2][ty], (f16)tile[tx * 4 + 3][ty]};
        *(half4_t*)&xt[(size_t)b * NTOK * DM + (size_t)(n0 + ty) * DM + c0 + tx * 4] = h;
    } else {
        int c = bid - 8192;                // 0..3071
        int i = c * 256 + tid;             // 0..786431
        int row = i >> 9, col = i & 511;
        float v = (row < 512) ? Wq[i] : (row < 1024) ? Wk[(row - 512) * 512 + col]
                                                     : Wv[(row - 1024) * 512 + col];
        wdst[i] = (f16)v;
        if (i < 1536)
            bdst[i] = (i < 512) ? bq[i] : (i < 1024) ? bk[i - 512] : bv[i - 1024];
        if (c < 64) rowsum[c * 256 + tid] = 0.f;  // 16384 f32
    }
}

// ---------------- mid: convert_w (blocks 0..1023) + transpose_v (1024..9215) ----------------
__global__ __launch_bounds__(256)
void mid_kernel(const float* __restrict__ Wo, f16* __restrict__ woh,
                const f16* __restrict__ vtok, f16* __restrict__ vh) {
    __shared__ f16 tile[32][36];
    int bid = blockIdx.x, tid = threadIdx.x;
    if (bid < 1024) {
        int i = bid * 256 + tid;
        woh[i] = (f16)Wo[i];
    } else {
        int c = bid - 1024;                // 0..8191
        int b = c >> 9, byy = (c >> 5) & 15, bxx = c & 31;
        int n0 = bxx * 32, c0 = byy * 32;
        int tx = tid & 7, ty = tid >> 3;   // 8 x 32
        const f16* src = vtok + (size_t)b * NTOK * DM + (size_t)(n0 + ty) * DM + c0 + tx * 4;
        half4_t v = *(const half4_t*)src;
        tile[ty][tx * 4 + 0] = v[0]; tile[ty][tx * 4 + 1] = v[1];
        tile[ty][tx * 4 + 2] = v[2]; tile[ty][tx * 4 + 3] = v[3];
        __syncthreads();
        half4_t h = {tile[tx * 4 + 0][ty], tile[tx * 4 + 1][ty],
                     tile[tx * 4 + 2][ty], tile[tx * 4 + 3][ty]};
        *(half4_t*)&vh[(size_t)b * DM * NTOK + (size_t)(c0 + ty) * NTOK + n0 + tx * 4] = h;
    }
}

// ---------------- NT GEMM: D[i][j] = sum_k A[i][k]*B[j][k], 128x128 tile, 4 waves ----------------
// BK template: 64 (32KB LDS, default) or 128 (64KB LDS — only for grids <= 2 blocks/CU where
// actual residency is grid-bound, e.g. PV's 512 blocks; halves the vmcnt(0)+barrier drains).
// Both-sides XOR swizzle generalized to SPR=BK/8 slots/row, mask SPR-1 (2-way residual, free).
// T1 XCD-aware bijective block remap (r9). XB extra streaming-role blocks fill stall bubbles
// of UNDER-FILLED dispatches only (r10/r11 lesson): MODE 3 hosts finalize (8 rows/block).
// MODE 0: QKV — gj<1024: f16 qk=D+bias[gj]; gj>=1024: f16 vtok[z][gi][gj-1024]=D+bias[gj]
// MODE 2: scores — e=exp(min(D*scale,14)-4) -> f16 e-slot (upper 2KB of attn row) + rowsum atomics
// MODE 3: out-proj — f32 out0 = D + bias[gi] + resid   (+ finalize role blocks)
// MODE 5: PV — f16 out = D * (1/rowsum[gi])
template<int MODE, int KC, int BK, int GX, int GY, int XB>
__global__ __launch_bounds__(256)
void gemm_nt(const f16* __restrict__ A, const f16* __restrict__ B, void* __restrict__ Cout,
             const float* __restrict__ bias, const float* __restrict__ resid,
             f16* __restrict__ aux, float* __restrict__ rowsum, float* __restrict__ fin,
             int ldA, int ldB, int ldC,
             long sA, long sB, long sC, long sR, float scale) {
    __shared__ f16 As[128 * BK];
    __shared__ f16 Bs[128 * BK];

    constexpr int NWG = GX * GY * NB;
    constexpr int SPR = BK / 8;          // 16B slots per row
    int flat = blockIdx.x;
    int tid = threadIdx.x;

    if (MODE == 3 && XB > 0 && flat >= NWG) {
        // ---- finalize role: 8 exclusive attn rows; read-all -> sync -> write-all ----
        int row0 = (flat - NWG) * 8;
        const f16* eb = (const f16*)fin;
        half4_t h[8];
#pragma unroll
        for (int rr = 0; rr < 8; ++rr)
            h[rr] = *(const half4_t*)(eb + (size_t)(row0 + rr) * 2048 + 1024 + tid * 4);
        __syncthreads();
#pragma unroll
        for (int rr = 0; rr < 8; ++rr) {
            int row = row0 + rr;
            float inv = 1.0f / rowsum[row];
            float4 o = {(float)h[rr][0] * inv, (float)h[rr][1] * inv,
                        (float)h[rr][2] * inv, (float)h[rr][3] * inv};
            *(float4*)(fin + (size_t)row * 1024 + tid * 4) = o;
        }
        return;
    }

    // T1: XCD-aware bijective remap (NWG % 8 == 0 for all instantiations)
    int w = (flat & 7) * (NWG >> 3) + (flat >> 3);
    int bx = w % GX, by = (w / GX) % GY, bz = w / (GX * GY);

    int z = bz;
    const f16* Ab = A + (size_t)z * sA;
    const f16* Bb = B + (size_t)z * sB;
    int wave = tid >> 6, lane = tid & 63;
    int wr = wave >> 1, wc = wave & 1;
    int tI = by * 128, tJ = bx * 128;

    f32x4 acc[4][4];
#pragma unroll
    for (int m = 0; m < 4; ++m)
#pragma unroll
        for (int n = 0; n < 4; ++n) acc[m][n] = (f32x4){0.f, 0.f, 0.f, 0.f};

    int frow = lane & 15, fks = lane >> 4;   // fragment row-low, 16B-slot base

    for (int k0 = 0; k0 < KC; k0 += BK) {
        // STAGE: 128*SPR 16B-slots each for A,B; linear LDS dest, source col inverse-swizzled
#pragma unroll
        for (int h = 0; h < (128 * SPR) / 256; ++h) {
            int L = h * 256 + tid;               // slot id
            int r = L / SPR;                     // row 0..127
            int gc = ((L & (SPR - 1)) ^ (r & (SPR - 1))) * 8;
            gload16(Ab + (size_t)(tI + r) * ldA + k0 + gc, &As[L * 8]);
            gload16(Bb + (size_t)(tJ + r) * ldB + k0 + gc, &Bs[L * 8]);
        }
        asm volatile("s_waitcnt vmcnt(0)" ::: "memory");
        __syncthreads();

#pragma unroll
        for (int ks = 0; ks < BK / 32; ++ks) {
            half8 af[4], bf[4];
            int s = ks * 4 + fks;                // natural 16B-slot 0..SPR-1
#pragma unroll
            for (int m = 0; m < 4; ++m) {
                int R = wr * 64 + m * 16 + frow;
                af[m] = *(const half8*)&As[R * BK + ((s ^ (R & (SPR - 1))) << 3)];
            }
#pragma unroll
            for (int n = 0; n < 4; ++n) {
                int R = wc * 64 + n * 16 + frow;
                bf[n] = *(const half8*)&Bs[R * BK + ((s ^ (R & (SPR - 1))) << 3)];
            }
#pragma unroll
            for (int m = 0; m < 4; ++m)
#pragma unroll
                for (int n = 0; n < 4; ++n)
                    acc[m][n] = __builtin_amdgcn_mfma_f32_16x16x32_f16(af[m], bf[n], acc[m][n], 0, 0, 0);
        }
        __syncthreads();
    }

    // epilogue: D row = (lane>>4)*4 + r, col = lane&15  (verified m89 mapping)
    int ro = (lane >> 4) * 4, co = lane & 15;
#pragma unroll
    for (int m = 0; m < 4; ++m) {
#pragma unroll
        for (int r = 0; r < 4; ++r) {
            int gi = tI + wr * 64 + m * 16 + ro + r;
            float rs = 0.f, inv = 0.f;
            if (MODE == 5) inv = 1.0f / rowsum[z * 1024 + gi];
#pragma unroll
            for (int n = 0; n < 4; ++n) {
                int gj = tJ + wc * 64 + n * 16 + co;
                float v = acc[m][n][r];
                if (MODE == 0) {
                    v += bias[gj];
                    if (gj < 1024)   // block-uniform branch (tile never straddles 1024)
                        ((f16*)Cout)[(size_t)z * sC + (size_t)gi * ldC + gj] = (f16)v;
                    else             // V token-major, coalesced
                        aux[(size_t)z * 524288 + (size_t)gi * 512 + (gj - 1024)] = (f16)v;
                } else if (MODE == 2) {
                    float e = __expf(fminf(v * scale, 14.f) - 4.f);
                    // e-slot: f16 in the upper 2KB of attn row gi's 4KB slot
                    ((f16*)Cout)[((size_t)z * 1024 + gi) * 2048 + 1024 + gj] = (f16)e;
                    rs += e;
                } else if (MODE == 3) {
                    ((float*)Cout)[(size_t)z * sC + (size_t)gi * ldC + gj] =
                        v + bias[gi] + resid[(size_t)z * sR + (size_t)gi * ldC + gj];
                } else {  // MODE 5
                    ((f16*)Cout)[(size_t)z * sC + (size_t)gi * ldC + gj] = (f16)(v * inv);
                }
            }
            if (MODE == 2) {
                rs += __shfl_xor(rs, 1, 16);
                rs += __shfl_xor(rs, 2, 16);
                rs += __shfl_xor(rs, 4, 16);
                rs += __shfl_xor(rs, 8, 16);
                if ((lane & 15) == 0) atomicAdd(&rowsum[z * 1024 + gi], rs);
            }
        }
    }
}

extern "C" void kernel_launch(void* const* d_in, const int* in_sizes, int n_in,
                              void* d_out, int out_size, void* d_ws, size_t ws_size,
                              hipStream_t stream) {
    const float* x  = (const float*)d_in[0];
    const float* Wq = (const float*)d_in[1];
    const float* bq = (const float*)d_in[2];
    const float* Wk = (const float*)d_in[3];
    const float* bk = (const float*)d_in[4];
    const float* Wv = (const float*)d_in[5];
    const float* bv = (const float*)d_in[6];
    const float* Wo = (const float*)d_in[7];
    const float* bo = (const float*)d_in[8];

    float* out0 = (float*)d_out;                           // [16][512][1024]
    float* attn = (float*)d_out + (size_t)NB * DM * NTOK;  // [16][1024][1024] f32 (+e16 slots)

    // workspace layout (f16 units), peak 34,376,704 units = 68.75 MB (proven budget)
    f16* ws    = (f16*)d_ws;
    f16* xt    = ws;                        // [B][N][512]   8,388,608 (dead after QKV)
    f16* oh    = ws;                        // [B][N][512]   alias of xt
    f16* qk    = ws + 8388608;              // [B][N][1024] 16,777,216 (q cols 0..511, k cols 512..1023)
    f16* vh    = ws + 25165824;             // [B][512][N]   8,388,608
    f16* wqkvh = ws + 33554432;             // [1536][512]     786,432
    f16* woh   = ws + 33554432;             // [512][512]    alias of wqkvh
    float* bqkv   = (float*)(ws + 34340864);  // [1536] f32
    float* rowsum = (float*)(ws + 34343936);  // [16384] f32

    // vtok lives in the out0 region of d_out (dead until the final GEMM)
    f16* vtok = (f16*)out0;                 // [B][N][512] f16 = 16 MB of out0's 32 MB

    const long sTok   = (long)NTOK * DM;      // 524288
    const long sQK    = (long)NTOK * 1024;    // 1048576
    const long sEslot = (long)NTOK * 2048;    // 2097152 (f16 units per batch of e-slot rows)
    const float scal = 0.044194173824159216f;  // 1/sqrt(512)

    // 1) prep: x transpose+convert, W_qkv concat-convert, bias concat, rowsum zero
    prep_kernel<<<8192 + 3072, 256, 0, stream>>>(x, xt, Wq, Wk, Wv, bq, bk, bv,
                                                 wqkvh, bqkv, rowsum);

    // 2) fused QKV: q,k -> qk[b][tok][0..1023]; V -> vtok[b][tok][0..511]
    gemm_nt<0, 512, 64, 12, 8, 0><<<12 * 8 * NB, 256, 0, stream>>>(xt, wqkvh, qk, bqkv, nullptr,
        vtok, nullptr, nullptr, 512, 512, 1024, sTok, 0, sQK, 0, 0.f);

    // 3) mid: Wo convert (woh aliases dead wqkvh) + vtok -> vh channel-major
    mid_kernel<<<1024 + 8192, 256, 0, stream>>>(Wo, woh, vtok, vh);

    // 4) scores: e = exp(min(s*scal,14)-4) -> f16 e-slots in attn region + rowsum atomics
    gemm_nt<2, 512, 64, 8, 8, 0><<<8 * 8 * NB, 256, 0, stream>>>(qk, qk + 512, attn,
        nullptr, nullptr, nullptr, rowsum, nullptr, 1024, 1024, 0, sQK, sQK, 0, 0, scal);

    // 5) PV: BK=128 (512-block grid => residency grid-bound at 2/CU, drains 16 -> 8)
    gemm_nt<5, 1024, 128, 4, 8, 0><<<4 * 8 * NB, 256, 0, stream>>>((const f16*)attn + 1024, vh, oh,
        nullptr, nullptr, nullptr, rowsum, nullptr, 2048, 1024, 512, sEslot, sTok, sTok, 0, 0.f);

    // 6) out0 = Wo·O^T + bo + x, plus 2048 finalize-role blocks (e16 -> normalized f32 attn)
    gemm_nt<3, 512, 64, 8, 4, 2048><<<8 * 4 * NB + 2048, 256, 0, stream>>>(woh, oh, out0, bo, x,
        nullptr, rowsum, attn, 512, 512, 1024, 0, sTok, sTok, sTok, 0.f);
}